// Round 12
// baseline (190.588 us; speedup 1.0000x reference)
//
#include <hip/hip_runtime.h>
#include <hip/hip_bf16.h>
#include <cstdint>
#include <cstddef>

#define BATCH 8192
#define IDIM  768
#define JDIM  768
#define GRID  5
#define KDIM  (IDIM * GRID)   // 3840

// ---------------- helpers ----------------

__device__ __forceinline__ unsigned short f2bf(float f) {
    unsigned int u = __float_as_uint(f);
    u += 0x7fffu + ((u >> 16) & 1u);
    return (unsigned short)(u >> 16);
}

typedef __bf16 bf16x8 __attribute__((ext_vector_type(8)));
typedef float  f32x4  __attribute__((ext_vector_type(4)));
typedef unsigned short ushortx4 __attribute__((ext_vector_type(4)));
typedef unsigned short ushortx8 __attribute__((ext_vector_type(8)));

__device__ __forceinline__ void async_copy16(const void* gsrc, void* ldsdst) {
    __builtin_amdgcn_global_load_lds(
        (const __attribute__((address_space(1))) unsigned int*)gsrc,
        (__attribute__((address_space(3))) unsigned int*)ldsdst,
        16, 0, 0);
}

// ---------------- fused precompute: Wt3 + bias + basis (ONE dispatch) -------
// r12: r11 showed non-GEMM wall time is a constant ~92us (60% of total) while
// the 3 prep dispatches only need ~20us of kernel time -> fuse them.
//  blocks [0,288):  Wt3 fragment-pack (r9-verified layout) ; blocks [0,12)
//                   additionally compute bias[j] = sum_i shift[i,j] directly
//                   (full-i sweep, no memset, no atomics).
//  blocks [288,3360): basis, 8 i's/thread, 16-B ushortx8 stores (G13).
// Wt3 layout: Wt3[ks(120)][jf(48)][lane(64)][8], elem = coeffs[i][j][g]*scale,
//   j = jf*16+(lane&15), k = ks*32+(lane>>4)*8+e, k = g*768+i.

#define WT_I 32
#define WT_J 64
#define NJF  (JDIM / 16)      // 48
#define NKS  (KDIM / 32)      // 120
#define WT_BLOCKS  ((IDIM / WT_I) * (JDIM / WT_J))          // 288
#define BAS_BLOCKS ((BATCH * (IDIM / 8)) / 256)             // 3072

__global__ __launch_bounds__(256)
void prep_kernel(const float* __restrict__ x,
                 const float* __restrict__ coeffs,
                 const float* __restrict__ scale,
                 const float* __restrict__ shift,
                 unsigned short* __restrict__ Wt3,
                 unsigned short* __restrict__ Abas,
                 float* __restrict__ bias) {
    const int bx = blockIdx.x;
    if (bx < WT_BLOCKS) {
        __shared__ __align__(16) unsigned short tile[GRID][WT_J][WT_I + 4]; // pad->36
        __shared__ float red[4][WT_J];
        const int t  = threadIdx.x;
        const int i0 = (bx / (JDIM / WT_J)) * WT_I;
        const int j0 = (bx % (JDIM / WT_J)) * WT_J;
        const int jj = t & 63;

        // ---- bias: only the 12 blocks with i0==0; full-i sweep, no atomics
        if (bx < (JDIM / WT_J)) {
            float s = 0.f;
            for (int i = (t >> 6); i < IDIM; i += 4)
                s += shift[(size_t)i * JDIM + j0 + jj];
            red[t >> 6][jj] = s;
            __syncthreads();
            if (t < WT_J)
                bias[j0 + t] = red[0][t] + red[1][t] + red[2][t] + red[3][t];
        }

        // ---- Wt3 pack (r9-verified)
#pragma unroll
        for (int it = 0; it < (WT_I * WT_J) / 256; ++it) {          // 8 iters
            const int ii = it * 4 + (t >> 6);
            const int i = i0 + ii, j = j0 + jj;
            const float* cp = &coeffs[((size_t)i * JDIM + j) * GRID];
            const float  sc = scale[(size_t)i * JDIM + j];
#pragma unroll
            for (int g = 0; g < GRID; ++g)
                tile[g][jj][ii] = f2bf(cp[g] * sc);
        }
        __syncthreads();

        // slot s: h=s&1, lane=(s>>1)&63, q=s>>7: jf_l=q&3, g=q>>2
#pragma unroll
        for (int it = 0; it < 10; ++it) {
            const int s    = it * 256 + t;
            const int h    = s & 1;
            const int lane = (s >> 1) & 63;
            const int q    = s >> 7;
            const int jf_l = q & 3;
            const int g    = q >> 2;
            const int i_loc = (lane >> 4) * 8 + h * 4;
            const int j_loc = jf_l * 16 + (lane & 15);
            ushortx4 v = *(const ushortx4*)&tile[g][j_loc][i_loc];
            const int ks  = g * (IDIM / 32) + (i0 >> 5);
            const int jfg = (j0 >> 4) + jf_l;
            *(ushortx4*)&Wt3[((((size_t)ks * NJF + jfg) * 64 + lane) * 8) + h * 4] = v;
        }
    } else {
        // ---- basis: 8 i's per thread, 16-B loads (x2) and 16-B stores
        const int idx = (bx - WT_BLOCKS) * 256 + threadIdx.x;   // over BATCH*96
        const int b  = idx / (IDIM / 8);
        const int i8 = (idx - b * (IDIM / 8)) * 8;
        const float4 xv0 = *(const float4*)&x[(size_t)b * IDIM + i8];
        const float4 xv1 = *(const float4*)&x[(size_t)b * IDIM + i8 + 4];
        const float xs[8] = {xv0.x, xv0.y, xv0.z, xv0.w, xv1.x, xv1.y, xv1.z, xv1.w};
        float tv[8];
#pragma unroll
        for (int u = 0; u < 8; ++u) {
            // tanh(x) = 1 - 2/(e^{2x}+1); saturates correctly at +-inf
            const float e = __expf(2.f * xs[u]);
            tv[u] = 1.f - 2.f / (e + 1.f);
        }
#pragma unroll
        for (int g = 0; g < GRID; ++g) {
            const float gv = -1.f + 0.5f * (float)g;
            ushortx8 o;
#pragma unroll
            for (int u = 0; u < 8; ++u) {
                const float d = tv[u] - gv;
                o[u] = f2bf(__expf(-5.f * d * d));
            }
            *(ushortx8*)&Abas[(size_t)b * KDIM + g * IDIM + i8] = o;
        }
    }
}

// ---------------- MFMA GEMM (unchanged from r9/r11: 60.1us verified) -------
// C[8192,768] = Abas @ W^T + bias.  BM=128, BN=96, BK=64.
// Grid dim3(64,8): XCD = id%8 = m%8 -> A-panel L2 reuse (r3-verified).
// A: LDS, 3-deep global_load_lds pipeline, counted vmcnt (r8-verified).
// B: global->VGPR from fragment-packed Wt3, reg double-buffer (r11-verified).

#define BM 128
#define BN 96
#define BK 64
#define KT (KDIM / BK)   // 60

__global__ __launch_bounds__(256, 2)
void kan_gemm(const unsigned short* __restrict__ Abas,  // [BATCH][KDIM]
              const unsigned short* __restrict__ Wt3,   // packed [ks][jf][lane][8]
              const float* __restrict__ bias,           // [JDIM]
              float* __restrict__ out) {                // [BATCH][JDIM]
    __shared__ unsigned short As[3][BM * BK];  // 3 x 16 KB

    const int t    = threadIdx.x;
    const int lane = t & 63;
    const int wave = t >> 6;
    const int m0 = blockIdx.x * BM;
    const int n0 = blockIdx.y * BN;
    const int wm = (wave >> 1) * 64;
    const int wn = (wave & 1) * 48;

    f32x4 acc[4][3] = {};

    const int lrow = t >> 3;
    const int lc   = t & 7;
    const int cg   = lc ^ (lrow & 7);
    const int ldsoff = lrow * BK + lc * 8;
    const size_t abase = (size_t)(m0 + lrow) * KDIM + cg * 8;

    auto stage_a = [&](int buf, int kt_el) {
#pragma unroll
        for (int s = 0; s < 4; ++s)
            async_copy16(&Abas[abase + (size_t)(32 * s) * KDIM + kt_el],
                         &As[buf][ldsoff + 32 * s * BK]);
    };

    const unsigned short* bp0 = Wt3 + (((size_t)((n0 + wn) >> 4) * 64 + lane) * 8);
    auto load_b = [&](int tt, bf16x8 (&dst)[6]) {
        const unsigned short* bp = bp0 + (size_t)(tt * 2) * (NJF * 512);
#pragma unroll
        for (int ks = 0; ks < 2; ++ks)
#pragma unroll
            for (int f = 0; f < 3; ++f)
                dst[ks * 3 + f] = *(const bf16x8*)&bp[(size_t)ks * (NJF * 512) + f * 512];
    };

    auto compute_tile = [&](int ab, const bf16x8 (&bfr)[6]) {
#pragma unroll
        for (int ks = 0; ks < 2; ++ks) {
            const int pc = ((ks * 4) + (lane >> 4)) ^ (lane & 7);
            bf16x8 af[4];
#pragma unroll
            for (int f = 0; f < 4; ++f)
                af[f] = *(const bf16x8*)&As[ab][(wm + f * 16 + (lane & 15)) * BK + pc * 8];
#pragma unroll
            for (int fm = 0; fm < 4; ++fm)
#pragma unroll
                for (int fn = 0; fn < 3; ++fn)
                    acc[fm][fn] = __builtin_amdgcn_mfma_f32_16x16x32_bf16(
                        af[fm], bfr[ks * 3 + fn], acc[fm][fn], 0, 0, 0);
        }
    };

    bf16x8 b0[6], b1[6];

    stage_a(0, 0);
    stage_a(1, BK);
    load_b(0, b0);

    int ac = 0, a2 = 2;
#pragma unroll 1
    for (int p = 0; p < (KT - 2) / 2; ++p) {
        int tt = 2 * p;
        stage_a(a2, (tt + 2) * BK);
        load_b(tt + 1, b1);
        asm volatile("s_waitcnt vmcnt(10)" ::: "memory");
        __builtin_amdgcn_s_barrier();
        __builtin_amdgcn_sched_barrier(0);
        compute_tile(ac, b0);
        __builtin_amdgcn_s_barrier();
        ac = (ac == 2) ? 0 : ac + 1;
        a2 = (a2 == 2) ? 0 : a2 + 1;
        ++tt;
        stage_a(a2, (tt + 2) * BK);
        load_b(tt + 1, b0);
        asm volatile("s_waitcnt vmcnt(10)" ::: "memory");
        __builtin_amdgcn_s_barrier();
        __builtin_amdgcn_sched_barrier(0);
        compute_tile(ac, b1);
        __builtin_amdgcn_s_barrier();
        ac = (ac == 2) ? 0 : ac + 1;
        a2 = (a2 == 2) ? 0 : a2 + 1;
    }
    {
        load_b(KT - 1, b1);
        asm volatile("s_waitcnt vmcnt(6)" ::: "memory");
        __builtin_amdgcn_s_barrier();
        __builtin_amdgcn_sched_barrier(0);
        compute_tile(ac, b0);          // B(58)
        __builtin_amdgcn_s_barrier();
        ac = (ac == 2) ? 0 : ac + 1;
    }
    {
        asm volatile("s_waitcnt vmcnt(0)" ::: "memory");
        __builtin_amdgcn_s_barrier();
        __builtin_amdgcn_sched_barrier(0);
        compute_tile(ac, b1);          // B(59)
    }

    // epilogue: D mapping col=lane&15, row=(lane>>4)*4+reg  [m89/m91]
    const int col   = lane & 15;
    const int rbase = (lane >> 4) * 4;
#pragma unroll
    for (int fm = 0; fm < 4; ++fm) {
#pragma unroll
        for (int fn = 0; fn < 3; ++fn) {
            const int j  = n0 + wn + fn * 16 + col;
            const float bj = bias[j];
#pragma unroll
            for (int r = 0; r < 4; ++r) {
                const int row = m0 + wm + fm * 16 + rbase + r;
                out[(size_t)row * JDIM + j] = acc[fm][fn][r] + bj;
            }
        }
    }
}

// ---------------- fallback (ws too small): slow but correct ----------------

__global__ __launch_bounds__(256)
void fallback_kernel(const float* __restrict__ x,
                     const float* __restrict__ coeffs,
                     const float* __restrict__ scale,
                     const float* __restrict__ shift,
                     float* __restrict__ out) {
    __shared__ float bas[KDIM];
    const int b = blockIdx.x;
    const int t = threadIdx.x;
    for (int i = t; i < IDIM; i += 256) {
        float tv = tanhf(x[(size_t)b * IDIM + i]);
#pragma unroll
        for (int g = 0; g < GRID; ++g) {
            float d = tv - (-1.0f + 0.5f * (float)g);
            bas[g * IDIM + i] = __expf(-5.0f * d * d);
        }
    }
    __syncthreads();
#pragma unroll
    for (int jj = 0; jj < 3; ++jj) {
        const int j = t + jj * 256;
        float acc = 0.f;
        for (int i = 0; i < IDIM; ++i) {
            const float sc = scale[(size_t)i * JDIM + j];
            const float* cp = &coeffs[((size_t)i * JDIM + j) * GRID];
            float s5 = 0.f;
#pragma unroll
            for (int g = 0; g < GRID; ++g) s5 += bas[g * IDIM + i] * cp[g];
            acc += s5 * sc + shift[(size_t)i * JDIM + j];
        }
        out[(size_t)b * JDIM + j] = acc;
    }
}

// ---------------- launch: TWO dispatches total ----------------

extern "C" void kernel_launch(void* const* d_in, const int* in_sizes, int n_in,
                              void* d_out, int out_size, void* d_ws, size_t ws_size,
                              hipStream_t stream) {
    const float* x      = (const float*)d_in[0];
    const float* coeffs = (const float*)d_in[1];
    const float* scale  = (const float*)d_in[2];
    const float* shift  = (const float*)d_in[3];
    float* out = (float*)d_out;

    const size_t wt_bytes   = (size_t)JDIM * KDIM * sizeof(unsigned short); // 5,898,240
    const size_t bias_off   = wt_bytes;
    const size_t bias_bytes = (size_t)JDIM * sizeof(float);
    const size_t bas_off    = bias_off + bias_bytes;
    const size_t bas_bytes  = (size_t)BATCH * KDIM * sizeof(unsigned short);
    const size_t need       = bas_off + bas_bytes;                          // ~68.8 MB

    if (ws_size >= need) {
        unsigned short* Wt3  = (unsigned short*)d_ws;
        float*          bias = (float*)((char*)d_ws + bias_off);
        unsigned short* Abas = (unsigned short*)((char*)d_ws + bas_off);

        prep_kernel<<<WT_BLOCKS + BAS_BLOCKS, 256, 0, stream>>>(
            x, coeffs, scale, shift, Wt3, Abas, bias);
        kan_gemm<<<dim3(BATCH / BM, JDIM / BN), 256, 0, stream>>>(Abas, Wt3, bias, out);
    } else {
        fallback_kernel<<<BATCH, 256, 0, stream>>>(x, coeffs, scale, shift, out);
    }
}

// Round 13
// 149.798 us; speedup vs baseline: 1.2723x; 1.2723x over previous
//
#include <hip/hip_runtime.h>
#include <hip/hip_bf16.h>
#include <cstdint>
#include <cstddef>

#define BATCH 8192
#define IDIM  768
#define JDIM  768
#define GRID  5
#define KDIM  (IDIM * GRID)   // 3840

// ---------------- helpers ----------------

__device__ __forceinline__ unsigned short f2bf(float f) {
    unsigned int u = __float_as_uint(f);
    u += 0x7fffu + ((u >> 16) & 1u);
    return (unsigned short)(u >> 16);
}

typedef __bf16 bf16x8 __attribute__((ext_vector_type(8)));
typedef float  f32x4  __attribute__((ext_vector_type(4)));
typedef unsigned short ushortx4 __attribute__((ext_vector_type(4)));
typedef unsigned short ushortx8 __attribute__((ext_vector_type(8)));

__device__ __forceinline__ void async_copy16(const void* gsrc, void* ldsdst) {
    __builtin_amdgcn_global_load_lds(
        (const __attribute__((address_space(1))) unsigned int*)gsrc,
        (__attribute__((address_space(3))) unsigned int*)ldsdst,
        16, 0, 0);
}

// ---------------- fused precompute: Wt3 + bias + basis (ONE dispatch) -------
// r13 fix of the r12 regression: r12's bias path (12 blocks, 192 SEQUENTIAL
// strided loads, no unroll) was a ~70us straggler that gated the whole
// dispatch (PMC signature: dur 65-97us with VALUBusy 12%, occupancy 10% ->
// slowest-block-bound).  Bias now has DEDICATED blocks with #pragma unroll 16
// (16 loads in flight -> ~5us); Wt-pack blocks do only the pack.
//  blocks [0,288):        Wt3 fragment-pack (r9-verified layout)
//  blocks [288,300):      bias[j] = sum_i shift[i,j]  (12 blocks, 64 j each)
//  blocks [300,300+3072): basis, 8 i's/thread, 16-B ushortx8 stores (G13)
// Wt3 layout: Wt3[ks(120)][jf(48)][lane(64)][8], elem = coeffs[i][j][g]*scale,
//   j = jf*16+(lane&15), k = ks*32+(lane>>4)*8+e, k = g*768+i.

#define WT_I 32
#define WT_J 64
#define NJF  (JDIM / 16)      // 48
#define NKS  (KDIM / 32)      // 120
#define WT_BLOCKS   ((IDIM / WT_I) * (JDIM / WT_J))          // 288
#define BIAS_BLOCKS (JDIM / 64)                              // 12
#define BAS_BLOCKS  ((BATCH * (IDIM / 8)) / 256)             // 3072
#define BAS_BASE    (WT_BLOCKS + BIAS_BLOCKS)                // 300

__global__ __launch_bounds__(256)
void prep_kernel(const float* __restrict__ x,
                 const float* __restrict__ coeffs,
                 const float* __restrict__ scale,
                 const float* __restrict__ shift,
                 unsigned short* __restrict__ Wt3,
                 unsigned short* __restrict__ Abas,
                 float* __restrict__ bias) {
    const int bx = blockIdx.x;
    if (bx < WT_BLOCKS) {
        // ---- Wt3 fragment-pack (r9-verified; no bias work here anymore)
        __shared__ __align__(16) unsigned short tile[GRID][WT_J][WT_I + 4]; // pad->36
        const int t  = threadIdx.x;
        const int i0 = (bx / (JDIM / WT_J)) * WT_I;
        const int j0 = (bx % (JDIM / WT_J)) * WT_J;
        const int jj = t & 63;

#pragma unroll
        for (int it = 0; it < (WT_I * WT_J) / 256; ++it) {          // 8 iters
            const int ii = it * 4 + (t >> 6);
            const int i = i0 + ii, j = j0 + jj;
            const float* cp = &coeffs[((size_t)i * JDIM + j) * GRID];
            const float  sc = scale[(size_t)i * JDIM + j];
#pragma unroll
            for (int g = 0; g < GRID; ++g)
                tile[g][jj][ii] = f2bf(cp[g] * sc);
        }
        __syncthreads();

        // slot s: h=s&1, lane=(s>>1)&63, q=s>>7: jf_l=q&3, g=q>>2
#pragma unroll
        for (int it = 0; it < 10; ++it) {
            const int s    = it * 256 + t;
            const int h    = s & 1;
            const int lane = (s >> 1) & 63;
            const int q    = s >> 7;
            const int jf_l = q & 3;
            const int g    = q >> 2;
            const int i_loc = (lane >> 4) * 8 + h * 4;
            const int j_loc = jf_l * 16 + (lane & 15);
            ushortx4 v = *(const ushortx4*)&tile[g][j_loc][i_loc];
            const int ks  = g * (IDIM / 32) + (i0 >> 5);
            const int jfg = (j0 >> 4) + jf_l;
            *(ushortx4*)&Wt3[((((size_t)ks * NJF + jfg) * 64 + lane) * 8) + h * 4] = v;
        }
    } else if (bx < BAS_BASE) {
        // ---- bias: 12 dedicated blocks, 64 j each; 4 threads/j x 192 i,
        //      unroll 16 -> 16 loads in flight (the r12 straggler fix)
        __shared__ float red[4][64];
        const int t  = threadIdx.x;
        const int j0 = (bx - WT_BLOCKS) * 64;
        const int jj = t & 63;
        const int q  = t >> 6;
        float s = 0.f;
#pragma unroll 16
        for (int i = q; i < IDIM; i += 4)
            s += shift[(size_t)i * JDIM + j0 + jj];
        red[q][jj] = s;
        __syncthreads();
        if (t < 64)
            bias[j0 + t] = red[0][t] + red[1][t] + red[2][t] + red[3][t];
    } else {
        // ---- basis: 8 i's per thread, 16-B loads (x2) and 16-B stores
        const int idx = (bx - BAS_BASE) * 256 + threadIdx.x;   // over BATCH*96
        const int b  = idx / (IDIM / 8);
        const int i8 = (idx - b * (IDIM / 8)) * 8;
        const float4 xv0 = *(const float4*)&x[(size_t)b * IDIM + i8];
        const float4 xv1 = *(const float4*)&x[(size_t)b * IDIM + i8 + 4];
        const float xs[8] = {xv0.x, xv0.y, xv0.z, xv0.w, xv1.x, xv1.y, xv1.z, xv1.w};
        float tv[8];
#pragma unroll
        for (int u = 0; u < 8; ++u) {
            // tanh(x) = 1 - 2/(e^{2x}+1); saturates correctly at +-inf
            const float e = __expf(2.f * xs[u]);
            tv[u] = 1.f - 2.f / (e + 1.f);
        }
#pragma unroll
        for (int g = 0; g < GRID; ++g) {
            const float gv = -1.f + 0.5f * (float)g;
            ushortx8 o;
#pragma unroll
            for (int u = 0; u < 8; ++u) {
                const float d = tv[u] - gv;
                o[u] = f2bf(__expf(-5.f * d * d));
            }
            *(ushortx8*)&Abas[(size_t)b * KDIM + g * IDIM + i8] = o;
        }
    }
}

// ---------------- MFMA GEMM (unchanged from r9/r11: 60.1us verified) -------
// C[8192,768] = Abas @ W^T + bias.  BM=128, BN=96, BK=64.
// Grid dim3(64,8): XCD = id%8 = m%8 -> A-panel L2 reuse (r3-verified).
// A: LDS, 3-deep global_load_lds pipeline, counted vmcnt (r8-verified).
// B: global->VGPR from fragment-packed Wt3, reg double-buffer (r11-verified).

#define BM 128
#define BN 96
#define BK 64
#define KT (KDIM / BK)   // 60

__global__ __launch_bounds__(256, 2)
void kan_gemm(const unsigned short* __restrict__ Abas,  // [BATCH][KDIM]
              const unsigned short* __restrict__ Wt3,   // packed [ks][jf][lane][8]
              const float* __restrict__ bias,           // [JDIM]
              float* __restrict__ out) {                // [BATCH][JDIM]
    __shared__ unsigned short As[3][BM * BK];  // 3 x 16 KB

    const int t    = threadIdx.x;
    const int lane = t & 63;
    const int wave = t >> 6;
    const int m0 = blockIdx.x * BM;
    const int n0 = blockIdx.y * BN;
    const int wm = (wave >> 1) * 64;
    const int wn = (wave & 1) * 48;

    f32x4 acc[4][3] = {};

    const int lrow = t >> 3;
    const int lc   = t & 7;
    const int cg   = lc ^ (lrow & 7);
    const int ldsoff = lrow * BK + lc * 8;
    const size_t abase = (size_t)(m0 + lrow) * KDIM + cg * 8;

    auto stage_a = [&](int buf, int kt_el) {
#pragma unroll
        for (int s = 0; s < 4; ++s)
            async_copy16(&Abas[abase + (size_t)(32 * s) * KDIM + kt_el],
                         &As[buf][ldsoff + 32 * s * BK]);
    };

    const unsigned short* bp0 = Wt3 + (((size_t)((n0 + wn) >> 4) * 64 + lane) * 8);
    auto load_b = [&](int tt, bf16x8 (&dst)[6]) {
        const unsigned short* bp = bp0 + (size_t)(tt * 2) * (NJF * 512);
#pragma unroll
        for (int ks = 0; ks < 2; ++ks)
#pragma unroll
            for (int f = 0; f < 3; ++f)
                dst[ks * 3 + f] = *(const bf16x8*)&bp[(size_t)ks * (NJF * 512) + f * 512];
    };

    auto compute_tile = [&](int ab, const bf16x8 (&bfr)[6]) {
#pragma unroll
        for (int ks = 0; ks < 2; ++ks) {
            const int pc = ((ks * 4) + (lane >> 4)) ^ (lane & 7);
            bf16x8 af[4];
#pragma unroll
            for (int f = 0; f < 4; ++f)
                af[f] = *(const bf16x8*)&As[ab][(wm + f * 16 + (lane & 15)) * BK + pc * 8];
#pragma unroll
            for (int fm = 0; fm < 4; ++fm)
#pragma unroll
                for (int fn = 0; fn < 3; ++fn)
                    acc[fm][fn] = __builtin_amdgcn_mfma_f32_16x16x32_bf16(
                        af[fm], bfr[ks * 3 + fn], acc[fm][fn], 0, 0, 0);
        }
    };

    bf16x8 b0[6], b1[6];

    stage_a(0, 0);
    stage_a(1, BK);
    load_b(0, b0);

    int ac = 0, a2 = 2;
#pragma unroll 1
    for (int p = 0; p < (KT - 2) / 2; ++p) {
        int tt = 2 * p;
        stage_a(a2, (tt + 2) * BK);
        load_b(tt + 1, b1);
        asm volatile("s_waitcnt vmcnt(10)" ::: "memory");
        __builtin_amdgcn_s_barrier();
        __builtin_amdgcn_sched_barrier(0);
        compute_tile(ac, b0);
        __builtin_amdgcn_s_barrier();
        ac = (ac == 2) ? 0 : ac + 1;
        a2 = (a2 == 2) ? 0 : a2 + 1;
        ++tt;
        stage_a(a2, (tt + 2) * BK);
        load_b(tt + 1, b0);
        asm volatile("s_waitcnt vmcnt(10)" ::: "memory");
        __builtin_amdgcn_s_barrier();
        __builtin_amdgcn_sched_barrier(0);
        compute_tile(ac, b1);
        __builtin_amdgcn_s_barrier();
        ac = (ac == 2) ? 0 : ac + 1;
        a2 = (a2 == 2) ? 0 : a2 + 1;
    }
    {
        load_b(KT - 1, b1);
        asm volatile("s_waitcnt vmcnt(6)" ::: "memory");
        __builtin_amdgcn_s_barrier();
        __builtin_amdgcn_sched_barrier(0);
        compute_tile(ac, b0);          // B(58)
        __builtin_amdgcn_s_barrier();
        ac = (ac == 2) ? 0 : ac + 1;
    }
    {
        asm volatile("s_waitcnt vmcnt(0)" ::: "memory");
        __builtin_amdgcn_s_barrier();
        __builtin_amdgcn_sched_barrier(0);
        compute_tile(ac, b1);          // B(59)
    }

    // epilogue: D mapping col=lane&15, row=(lane>>4)*4+reg  [m89/m91]
    const int col   = lane & 15;
    const int rbase = (lane >> 4) * 4;
#pragma unroll
    for (int fm = 0; fm < 4; ++fm) {
#pragma unroll
        for (int fn = 0; fn < 3; ++fn) {
            const int j  = n0 + wn + fn * 16 + col;
            const float bj = bias[j];
#pragma unroll
            for (int r = 0; r < 4; ++r) {
                const int row = m0 + wm + fm * 16 + rbase + r;
                out[(size_t)row * JDIM + j] = acc[fm][fn][r] + bj;
            }
        }
    }
}

// ---------------- fallback (ws too small): slow but correct ----------------

__global__ __launch_bounds__(256)
void fallback_kernel(const float* __restrict__ x,
                     const float* __restrict__ coeffs,
                     const float* __restrict__ scale,
                     const float* __restrict__ shift,
                     float* __restrict__ out) {
    __shared__ float bas[KDIM];
    const int b = blockIdx.x;
    const int t = threadIdx.x;
    for (int i = t; i < IDIM; i += 256) {
        float tv = tanhf(x[(size_t)b * IDIM + i]);
#pragma unroll
        for (int g = 0; g < GRID; ++g) {
            float d = tv - (-1.0f + 0.5f * (float)g);
            bas[g * IDIM + i] = __expf(-5.0f * d * d);
        }
    }
    __syncthreads();
#pragma unroll
    for (int jj = 0; jj < 3; ++jj) {
        const int j = t + jj * 256;
        float acc = 0.f;
        for (int i = 0; i < IDIM; ++i) {
            const float sc = scale[(size_t)i * JDIM + j];
            const float* cp = &coeffs[((size_t)i * JDIM + j) * GRID];
            float s5 = 0.f;
#pragma unroll
            for (int g = 0; g < GRID; ++g) s5 += bas[g * IDIM + i] * cp[g];
            acc += s5 * sc + shift[(size_t)i * JDIM + j];
        }
        out[(size_t)b * JDIM + j] = acc;
    }
}

// ---------------- launch: TWO dispatches total ----------------

extern "C" void kernel_launch(void* const* d_in, const int* in_sizes, int n_in,
                              void* d_out, int out_size, void* d_ws, size_t ws_size,
                              hipStream_t stream) {
    const float* x      = (const float*)d_in[0];
    const float* coeffs = (const float*)d_in[1];
    const float* scale  = (const float*)d_in[2];
    const float* shift  = (const float*)d_in[3];
    float* out = (float*)d_out;

    const size_t wt_bytes   = (size_t)JDIM * KDIM * sizeof(unsigned short); // 5,898,240
    const size_t bias_off   = wt_bytes;
    const size_t bias_bytes = (size_t)JDIM * sizeof(float);
    const size_t bas_off    = bias_off + bias_bytes;
    const size_t bas_bytes  = (size_t)BATCH * KDIM * sizeof(unsigned short);
    const size_t need       = bas_off + bas_bytes;                          // ~68.8 MB

    if (ws_size >= need) {
        unsigned short* Wt3  = (unsigned short*)d_ws;
        float*          bias = (float*)((char*)d_ws + bias_off);
        unsigned short* Abas = (unsigned short*)((char*)d_ws + bas_off);

        prep_kernel<<<WT_BLOCKS + BIAS_BLOCKS + BAS_BLOCKS, 256, 0, stream>>>(
            x, coeffs, scale, shift, Wt3, Abas, bias);
        kan_gemm<<<dim3(BATCH / BM, JDIM / BN), 256, 0, stream>>>(Abas, Wt3, bias, out);
    } else {
        fallback_kernel<<<BATCH, 256, 0, stream>>>(x, coeffs, scale, shift, out);
    }
}